// Round 1
// baseline (268.825 us; speedup 1.0000x reference)
//
#include <hip/hip_runtime.h>

// ---------- types ----------
typedef __attribute__((ext_vector_type(8))) short bf16x8;   // 8 bf16 (4 VGPRs)
typedef __attribute__((ext_vector_type(4))) float f32x4;    // MFMA accumulator

#define KSPLIT_V 16
#define KSTEPS_V 135   // 135*32*16 = 69120
#define KSTEPS_A 40    // 40*32 = 1280

// round-to-nearest-even f32 -> bf16 bits
__device__ __forceinline__ unsigned int f2bf(float f) {
    union { float f; unsigned int u; } v; v.f = f;
    return (v.u + 0x7FFFu + ((v.u >> 16) & 1u)) >> 16;
}
__device__ __forceinline__ unsigned int pack2(float a, float b) {
    return f2bf(a) | (f2bf(b) << 16);
}

// ---------- GEMM: C[512,512] += A[512,K] * W[K,512]  (bf16 MFMA, split-K partials) ----------
// MODE 0: A = cropped/moveaxis'd visual, row stride 138240 in source, K=69120
// MODE 1: A = audio, row stride 1280, K=1280
template<int MODE>
__global__ __launch_bounds__(256) void gemm_bf16(
    const float* __restrict__ s1, const float* __restrict__ s2,
    const float* __restrict__ W, float* __restrict__ part, int kSteps)
{
    __shared__ uint4 As[256];  // [kblk(4)][row(64)] 16B units, XOR-swizzled
    __shared__ uint4 Bs[256];  // [kblk(4)][col(64)] 16B units, XOR-swizzled

    const int tid = threadIdx.x;
    const int m0 = blockIdx.x * 64;
    const int n0 = blockIdx.y * 64;
    const int k0 = blockIdx.z * kSteps * 32;

    const int ROWSTR = (MODE == 0) ? 138240 : 1280;

    // A staging: thread -> (row, kblk); 8 contiguous k per thread
    const int a_row  = tid >> 2;     // 0..63
    const int a_kblk = tid & 3;      // 0..3
    const int grow = m0 + a_row;
    const float* abase = (grow < 256) ? (s1 + (size_t)grow * ROWSTR)
                                      : (s2 + (size_t)(grow - 256) * ROWSTR);
    const int a_u = (a_kblk * 64 + a_row) ^ ((a_kblk & 1) << 2);

    // B staging: thread -> (col, kblk); 8 strided k per thread (gather a column slice)
    const int b_col  = tid & 63;
    const int b_kblk = tid >> 6;
    const int b_u = (b_kblk * 64 + b_col) ^ ((b_kblk & 1) << 2);
    const float* wbase = W + n0 + b_col;

    // wave -> 32x32 quadrant
    const int lane = tid & 63;
    const int wave = tid >> 6;
    const int wrow = (wave >> 1) * 32;
    const int wcol = (wave & 1) * 32;
    const int l15 = lane & 15;
    const int lk  = lane >> 4;          // kblk for MFMA fragment
    const int swz = (lk & 1) << 2;
    const int ra0 = (lk * 64 + wrow + l15) ^ swz;
    const int ra1 = (lk * 64 + wrow + 16 + l15) ^ swz;
    const int rb0 = (lk * 64 + wcol + l15) ^ swz;
    const int rb1 = (lk * 64 + wcol + 16 + l15) ^ swz;

    const f32x4 fzero = {0.f, 0.f, 0.f, 0.f};
    f32x4 acc00 = fzero, acc01 = fzero, acc10 = fzero, acc11 = fzero;

    for (int ks = 0; ks < kSteps; ++ks) {
        const int kk = k0 + ks * 32;

        // --- stage A tile (64 rows x 32 k) as bf16
        {
            const int k = kk + a_kblk * 8;
            size_t off;
            if (MODE == 0) {
                // k = ((t*3 + c)*48 + r)*96 + x  ->  src off = c*46080 + t*9216 + (48+r)*96 + x
                const int x  = k % 96;
                const int q  = k / 96;
                const int r  = q % 48;
                const int q2 = q / 48;
                const int c  = q2 % 3;
                const int t  = q2 / 3;
                off = (size_t)c * 46080 + (size_t)t * 9216 + (size_t)(48 + r) * 96 + (size_t)x;
            } else {
                off = (size_t)k;
            }
            const float4 f0 = *(const float4*)(abase + off);
            const float4 f1 = *(const float4*)(abase + off + 4);
            uint4 p;
            p.x = pack2(f0.x, f0.y); p.y = pack2(f0.z, f0.w);
            p.z = pack2(f1.x, f1.y); p.w = pack2(f1.z, f1.w);
            As[a_u] = p;
        }
        // --- stage B tile (32 k x 64 cols) as bf16, transposed into [kblk][col] units
        {
            const float* wp = wbase + (size_t)(kk + b_kblk * 8) * 512;
            const float f0 = wp[0],    f1 = wp[512],  f2 = wp[1024], f3 = wp[1536];
            const float f4 = wp[2048], f5 = wp[2560], f6 = wp[3072], f7 = wp[3584];
            uint4 p;
            p.x = pack2(f0, f1); p.y = pack2(f2, f3);
            p.z = pack2(f4, f5); p.w = pack2(f6, f7);
            Bs[b_u] = p;
        }
        __syncthreads();

        const bf16x8 a0 = __builtin_bit_cast(bf16x8, As[ra0]);
        const bf16x8 a1 = __builtin_bit_cast(bf16x8, As[ra1]);
        const bf16x8 b0 = __builtin_bit_cast(bf16x8, Bs[rb0]);
        const bf16x8 b1 = __builtin_bit_cast(bf16x8, Bs[rb1]);
        acc00 = __builtin_amdgcn_mfma_f32_16x16x32_bf16(a0, b0, acc00, 0, 0, 0);
        acc01 = __builtin_amdgcn_mfma_f32_16x16x32_bf16(a0, b1, acc01, 0, 0, 0);
        acc10 = __builtin_amdgcn_mfma_f32_16x16x32_bf16(a1, b0, acc10, 0, 0, 0);
        acc11 = __builtin_amdgcn_mfma_f32_16x16x32_bf16(a1, b1, acc11, 0, 0, 0);

        __syncthreads();
    }

    // epilogue: write fp32 partials; C/D layout: col = lane&15, row = (lane>>4)*4 + reg
    float* outp = part + (size_t)blockIdx.z * (512 * 512);
    #define WR(ACC, M, N)                                                        \
        {                                                                        \
            const int col = n0 + wcol + (N)*16 + l15;                            \
            _Pragma("unroll")                                                    \
            for (int r = 0; r < 4; ++r) {                                        \
                const int row = m0 + wrow + (M)*16 + lk * 4 + r;                 \
                outp[(size_t)row * 512 + col] = ACC[r];                          \
            }                                                                    \
        }
    WR(acc00, 0, 0) WR(acc01, 0, 1) WR(acc10, 1, 0) WR(acc11, 1, 1)
    #undef WR
}

// ---------- reduce split-K partials + row L2 normalization ----------
// grid.x = 1024: rows 0..511 -> A (1 partial slot), rows 512..1023 -> V (KSPLIT_V slots)
__global__ __launch_bounds__(256) void norm_kernel(
    const float* __restrict__ partA, const float* __restrict__ partV,
    float* __restrict__ Aout, float* __restrict__ Vout)
{
    const int row = blockIdx.x;
    const int tid = threadIdx.x;
    const bool isV = row >= 512;
    const int r = isV ? (row - 512) : row;
    const int c0 = tid, c1 = tid + 256;

    float v0, v1;
    if (isV) {
        float s0 = 0.f, s1 = 0.f;
        #pragma unroll
        for (int z = 0; z < KSPLIT_V; ++z) {
            const float* p = partV + (size_t)z * (512 * 512) + (size_t)r * 512;
            s0 += p[c0]; s1 += p[c1];
        }
        v0 = s0; v1 = s1;
    } else {
        const float* p = partA + (size_t)r * 512;
        v0 = p[c0]; v1 = p[c1];
    }

    float ss = v0 * v0 + v1 * v1;
    #pragma unroll
    for (int off = 32; off > 0; off >>= 1) ss += __shfl_down(ss, off);
    __shared__ float sbuf[4];
    if ((tid & 63) == 0) sbuf[tid >> 6] = ss;
    __syncthreads();
    const float total = sbuf[0] + sbuf[1] + sbuf[2] + sbuf[3];
    const float inv = 1.f / fmaxf(sqrtf(total), 1e-12f);

    float* outp = (isV ? Vout : Aout) + (size_t)r * 512;
    outp[c0] = v0 * inv;
    outp[c1] = v1 * inv;
}

// ---------- per-sample contrastive loss ----------
// block i in 0..255; A,V are the normalized [512,512] embeddings
__global__ __launch_bounds__(256) void loss_kernel(
    const float* __restrict__ A, const float* __restrict__ V,
    float* __restrict__ lossArr)
{
    const int i = blockIdx.x;
    const int tid = threadIdx.x;
    __shared__ float a1s[512], a2s[512], v1s[512], v2s[512];
    __shared__ float red[4][8];

    {
        const float* a1p = A + (size_t)i * 512;
        const float* a2p = A + (size_t)(i + 256) * 512;
        const float* v1p = V + (size_t)i * 512;
        const float* v2p = V + (size_t)(i + 256) * 512;
        a1s[tid] = a1p[tid]; a1s[tid + 256] = a1p[tid + 256];
        a2s[tid] = a2p[tid]; a2s[tid + 256] = a2p[tid + 256];
        v1s[tid] = v1p[tid]; v1s[tid + 256] = v1p[tid + 256];
        v2s[tid] = v2p[tid]; v2s[tid + 256] = v2p[tid + 256];
    }
    __syncthreads();

    // denominator: sum_j exp(a1.v_j) + exp(a2.v_j); each thread owns 2 j's
    float den = 0.f;
    #pragma unroll
    for (int jj = 0; jj < 2; ++jj) {
        const int j = tid + jj * 256;
        const float4* vj = (const float4*)(V + (size_t)j * 512);
        float d1 = 0.f, d2 = 0.f;
        for (int k4 = 0; k4 < 128; ++k4) {
            const float4 vv = vj[k4];
            const int k = k4 * 4;
            d1 += a1s[k] * vv.x + a1s[k + 1] * vv.y + a1s[k + 2] * vv.z + a1s[k + 3] * vv.w;
            d2 += a2s[k] * vv.x + a2s[k + 1] * vv.y + a2s[k + 2] * vv.z + a2s[k + 3] * vv.w;
        }
        den += expf(d1) + expf(d2);
    }

    // 7 block-wide sums: den + 6 numerator dots
    float p[7];
    p[0] = den;
    #pragma unroll
    for (int q = 1; q < 7; ++q) p[q] = 0.f;
    #pragma unroll
    for (int kk = 0; kk < 2; ++kk) {
        const int k = tid + kk * 256;
        const float x1 = a1s[k], x2 = a2s[k], y1 = v1s[k], y2 = v2s[k];
        p[1] += x1 * y1; p[2] += x1 * y2; p[3] += x2 * y1;
        p[4] += x2 * y2; p[5] += x1 * x2; p[6] += y1 * y2;
    }
    #pragma unroll
    for (int q = 0; q < 7; ++q) {
        #pragma unroll
        for (int off = 32; off > 0; off >>= 1) p[q] += __shfl_down(p[q], off);
    }
    const int lane = tid & 63, w = tid >> 6;
    if (lane == 0) {
        #pragma unroll
        for (int q = 0; q < 7; ++q) red[w][q] = p[q];
    }
    __syncthreads();
    if (tid == 0) {
        float d[7];
        #pragma unroll
        for (int q = 0; q < 7; ++q) d[q] = red[0][q] + red[1][q] + red[2][q] + red[3][q];
        const float num = expf(d[1]) + expf(d[2]) + expf(d[3]) +
                          expf(d[4]) + expf(d[5]) + expf(d[6]);
        lossArr[i] = logf(d[0]) - logf(num);   // = -(log num - log den)
    }
}

// ---------- mean over 256 samples ----------
__global__ __launch_bounds__(256) void final_reduce(
    const float* __restrict__ lossArr, float* __restrict__ out)
{
    const int tid = threadIdx.x;
    float v = lossArr[tid];
    #pragma unroll
    for (int off = 32; off > 0; off >>= 1) v += __shfl_down(v, off);
    __shared__ float sbuf[4];
    if ((tid & 63) == 0) sbuf[tid >> 6] = v;
    __syncthreads();
    if (tid == 0) out[0] = (sbuf[0] + sbuf[1] + sbuf[2] + sbuf[3]) * (1.f / 256.f);
}

// ---------- launch ----------
extern "C" void kernel_launch(void* const* d_in, const int* in_sizes, int n_in,
                              void* d_out, int out_size, void* d_ws, size_t ws_size,
                              hipStream_t stream)
{
    (void)in_sizes; (void)n_in; (void)out_size; (void)ws_size;
    const float* a_1 = (const float*)d_in[0];
    const float* v_1 = (const float*)d_in[1];
    const float* a_2 = (const float*)d_in[2];
    const float* v_2 = (const float*)d_in[3];
    const float* W_a = (const float*)d_in[4];
    const float* W_v = (const float*)d_in[5];
    float* out = (float*)d_out;

    float* ws      = (float*)d_ws;
    float* partV   = ws;                                   // KSPLIT_V * 512*512 f32 (16 MB)
    float* partA   = partV + (size_t)KSPLIT_V * 512 * 512; // 512*512 f32 (1 MB)
    float* Anorm   = partA + 512 * 512;                    // 1 MB
    float* Vnorm   = Anorm + 512 * 512;                    // 1 MB
    float* lossArr = Vnorm + 512 * 512;                    // 1 KB

    gemm_bf16<0><<<dim3(8, 8, KSPLIT_V), 256, 0, stream>>>(v_1, v_2, W_v, partV, KSTEPS_V);
    gemm_bf16<1><<<dim3(8, 8, 1),        256, 0, stream>>>(a_1, a_2, W_a, partA, KSTEPS_A);
    norm_kernel<<<1024, 256, 0, stream>>>(partA, partV, Anorm, Vnorm);
    loss_kernel<<<256, 256, 0, stream>>>(Anorm, Vnorm, lossArr);
    final_reduce<<<1, 256, 0, stream>>>(lossArr, out);
}

// Round 3
// 199.088 us; speedup vs baseline: 1.3503x; 1.3503x over previous
//
#include <hip/hip_runtime.h>

typedef __attribute__((ext_vector_type(8))) short bf16x8;   // 8 bf16 (4 VGPRs)
typedef __attribute__((ext_vector_type(4))) float f32x4;    // MFMA accumulator

#define KSPLIT_V 16
#define KSPLIT_A 4

// pack two f32 -> one dword of 2 bf16 (RNE), single HW instruction
__device__ __forceinline__ unsigned int pk2(float a, float b) {
    unsigned int r;
    asm("v_cvt_pk_bf16_f32 %0, %1, %2" : "=v"(r) : "v"(a), "v"(b));
    return r;
}

// ---------------------------------------------------------------------------
// MODE 0: visual GEMM  (A = cropped visual, B = W_v k-major), partials out
// MODE 1: audio  GEMM  (A = audio,          B = W_a k-major), partials out
// MODE 2: similarity   (A = Anorm rows, B = Vnorm rows), exp/rowsum/diag out
// Tile: 128x128, BK=32, 512 threads = 8 waves (4 row x 2 col of 32x64)
// ---------------------------------------------------------------------------
template<int MODE>
__global__ __launch_bounds__(512) void mm_kernel(
    const float* __restrict__ s1, const float* __restrict__ s2,
    const float* __restrict__ Bsrc, float* __restrict__ outp,
    float* __restrict__ den, float* __restrict__ num)
{
    __shared__ uint4 As[512];   // [kblk(4)][row(128)] 8-k bf16 units, XOR swizzle
    __shared__ uint4 Bs[512];   // [kblk(4)][col(128)]

    const int tid = threadIdx.x;

    int m0, n0, k0, nsteps, z = 0;
    if (MODE == 0) {
        // XCD-chunked swizzle: XCD x gets lin in [32x, 32x+32) -> 2 z-slices,
        // all (m,n) of them co-resident -> A and B panel re-reads are L2-local.
        const int lin = (blockIdx.x & 7) * 32 + (blockIdx.x >> 3);
        z = lin >> 4;
        m0 = ((lin >> 2) & 3) * 128;
        n0 = (lin & 3) * 128;
        k0 = z * 4320;          // 4320 = 69120/16 = 135*32
        nsteps = 135;
    } else if (MODE == 1) {
        z = blockIdx.x >> 4;
        m0 = ((blockIdx.x >> 2) & 3) * 128;
        n0 = (blockIdx.x & 3) * 128;
        k0 = z * 320;           // 1280/4
        nsteps = 10;
    } else {
        m0 = (blockIdx.x >> 2) * 128;
        n0 = (blockIdx.x & 3) * 128;
        k0 = 0;
        nsteps = 16;            // K = 512
    }
    if (MODE != 2) outp += (size_t)z * (512 * 512);

    const int ROWSTR = (MODE == 0) ? 138240 : (MODE == 1 ? 1280 : 512);

    // --- staging thread mapping: one 8-k bf16 unit per thread per tile
    const int a_row = tid >> 2;       // 0..127
    const int a_kb  = tid & 3;        // 0..3
    const int b_col = tid & 127;      // 0..127
    const int b_kb  = tid >> 7;       // 0..3
    const int a_u = (a_kb * 128 + a_row) ^ (a_kb << 1);
    const int b_u = (b_kb * 128 + b_col) ^ (b_kb << 1);

    const int grow = m0 + a_row;
    const float* abase = (grow < 256) ? (s1 + (size_t)grow * ROWSTR)
                                      : (s2 + (size_t)(grow - 256) * ROWSTR);
    // crop mapping (MODE 0): within a 4608-k chunk the source is CONTIGUOUS:
    // off = c*46080 + t*9216 + 4608 + j,  j = k - (t*3+c)*4608
    int aoff, jj = 0, kglob = k0;
    if (MODE == 0) {
        const int ph = k0 / 4608;
        jj = k0 - ph * 4608;
        const int c = ph % 3, t = ph / 3;
        aoff = c * 46080 + t * 9216 + 4608 + jj + a_kb * 8;
    } else {
        aoff = k0 + a_kb * 8;
    }

    const float* bptr;
    if (MODE == 2) bptr = Bsrc + (size_t)(n0 + b_col) * 512 + b_kb * 8;
    else           bptr = Bsrc + (size_t)(k0 + b_kb * 8) * 512 + n0 + b_col;

    // --- wave tiling
    const int lane = tid & 63;
    const int wid  = tid >> 6;
    const int wrow = (wid >> 1) * 32;
    const int wcol = (wid & 1) * 64;
    const int l15  = lane & 15;
    const int lk   = lane >> 4;

    int ra[2], rb[4];
    #pragma unroll
    for (int m = 0; m < 2; ++m) ra[m] = (lk * 128 + wrow + m * 16 + l15) ^ (lk << 1);
    #pragma unroll
    for (int n = 0; n < 4; ++n) rb[n] = (lk * 128 + wcol + n * 16 + l15) ^ (lk << 1);

    f32x4 acc[2][4];
    #pragma unroll
    for (int m = 0; m < 2; ++m)
        #pragma unroll
        for (int n = 0; n < 4; ++n) acc[m][n] = f32x4{0.f, 0.f, 0.f, 0.f};

    // --- prologue: load step 0 into regs
    float4 A0 = *(const float4*)(abase + aoff);
    float4 A1 = *(const float4*)(abase + aoff + 4);
    float4 B0, B1; float bsr[8];
    if (MODE == 2) {
        B0 = *(const float4*)bptr; B1 = *(const float4*)(bptr + 4);
    } else {
        #pragma unroll
        for (int j = 0; j < 8; ++j) bsr[j] = bptr[(size_t)j * 512];
    }

    for (int ks = 0; ks < nsteps; ++ks) {
        // pack current regs -> LDS (v_cvt_pk_bf16_f32 pairs)
        uint4 pa;
        pa.x = pk2(A0.x, A0.y); pa.y = pk2(A0.z, A0.w);
        pa.z = pk2(A1.x, A1.y); pa.w = pk2(A1.z, A1.w);
        As[a_u] = pa;
        uint4 pb;
        if (MODE == 2) {
            pb.x = pk2(B0.x, B0.y); pb.y = pk2(B0.z, B0.w);
            pb.z = pk2(B1.x, B1.y); pb.w = pk2(B1.z, B1.w);
        } else {
            pb.x = pk2(bsr[0], bsr[1]); pb.y = pk2(bsr[2], bsr[3]);
            pb.z = pk2(bsr[4], bsr[5]); pb.w = pk2(bsr[6], bsr[7]);
        }
        Bs[b_u] = pb;
        __syncthreads();

        // issue next-step loads (T14: latency hides under the MFMA phase)
        const bool more = (ks + 1 < nsteps);
        float4 A0n, A1n, B0n, B1n; float bsn[8];
        if (more) {
            kglob += 32;
            if (MODE == 0) {
                aoff += 32; jj += 32;
                if (jj == 4608) {            // rare, block-uniform
                    jj = 0;
                    const int ph = kglob / 4608;
                    const int c = ph % 3, t = ph / 3;
                    aoff = c * 46080 + t * 9216 + 4608 + a_kb * 8;
                }
            } else {
                aoff += 32;
            }
            A0n = *(const float4*)(abase + aoff);
            A1n = *(const float4*)(abase + aoff + 4);
            if (MODE == 2) {
                bptr += 32;
                B0n = *(const float4*)bptr; B1n = *(const float4*)(bptr + 4);
            } else {
                bptr += 32 * 512;
                #pragma unroll
                for (int j = 0; j < 8; ++j) bsn[j] = bptr[(size_t)j * 512];
            }
        }

        // compute current step from LDS
        bf16x8 af[2], bfr[4];
        #pragma unroll
        for (int m = 0; m < 2; ++m) af[m] = __builtin_bit_cast(bf16x8, As[ra[m]]);
        #pragma unroll
        for (int n = 0; n < 4; ++n) bfr[n] = __builtin_bit_cast(bf16x8, Bs[rb[n]]);
        #pragma unroll
        for (int m = 0; m < 2; ++m)
            #pragma unroll
            for (int n = 0; n < 4; ++n)
                acc[m][n] = __builtin_amdgcn_mfma_f32_16x16x32_bf16(af[m], bfr[n], acc[m][n], 0, 0, 0);
        __syncthreads();

        if (more) {
            A0 = A0n; A1 = A1n;
            if (MODE == 2) { B0 = B0n; B1 = B1n; }
            else {
                #pragma unroll
                for (int j = 0; j < 8; ++j) bsr[j] = bsn[j];
            }
        }
    }

    // --- epilogue.  C/D layout: col = lane&15, row = (lane>>4)*4 + reg
    if (MODE != 2) {
        #pragma unroll
        for (int m = 0; m < 2; ++m)
            #pragma unroll
            for (int n = 0; n < 4; ++n) {
                const int col = n0 + wcol + n * 16 + l15;
                #pragma unroll
                for (int r = 0; r < 4; ++r) {
                    const int row = m0 + wrow + m * 16 + lk * 4 + r;
                    outp[(size_t)row * 512 + col] = acc[m][n][r];
                }
            }
    } else {
        // S[row,col] = a_row . v_col ; accumulate den[row&255] += sum_col exp(S),
        // and the 4 diagonal-family terms into num[row&255]
        #pragma unroll
        for (int m = 0; m < 2; ++m) {
            float rs[4] = {0.f, 0.f, 0.f, 0.f};
            #pragma unroll
            for (int n = 0; n < 4; ++n) {
                const int col = n0 + wcol + n * 16 + l15;
                #pragma unroll
                for (int r = 0; r < 4; ++r) {
                    const int row = m0 + wrow + m * 16 + lk * 4 + r;
                    const float e = __expf(acc[m][n][r]);
                    rs[r] += e;
                    if (((row - col) & 255) == 0) atomicAdd(num + (row & 255), e);
                }
            }
            #pragma unroll
            for (int r = 0; r < 4; ++r) {
                float v = rs[r];
                v += __shfl_xor(v, 1);
                v += __shfl_xor(v, 2);
                v += __shfl_xor(v, 4);
                v += __shfl_xor(v, 8);
                if (l15 == 0) {
                    const int row = m0 + wrow + m * 16 + lk * 4 + r;
                    atomicAdd(den + (row & 255), v);
                }
            }
        }
    }
}

// ---------- reduce split-K partials + row L2 normalization ----------
__global__ __launch_bounds__(256) void norm_kernel(
    const float* __restrict__ partA, const float* __restrict__ partV,
    float* __restrict__ Aout, float* __restrict__ Vout)
{
    const int row = blockIdx.x;          // 0..1023
    const int tid = threadIdx.x;
    const bool isV = row >= 512;
    const int r = isV ? (row - 512) : row;
    const int c0 = tid, c1 = tid + 256;

    float v0 = 0.f, v1 = 0.f;
    if (isV) {
        #pragma unroll
        for (int zz = 0; zz < KSPLIT_V; ++zz) {
            const float* p = partV + (size_t)zz * 262144 + (size_t)r * 512;
            v0 += p[c0]; v1 += p[c1];
        }
    } else {
        #pragma unroll
        for (int zz = 0; zz < KSPLIT_A; ++zz) {
            const float* p = partA + (size_t)zz * 262144 + (size_t)r * 512;
            v0 += p[c0]; v1 += p[c1];
        }
    }

    float ss = v0 * v0 + v1 * v1;
    #pragma unroll
    for (int off = 32; off > 0; off >>= 1) ss += __shfl_down(ss, off);
    __shared__ float sbuf[4];
    if ((tid & 63) == 0) sbuf[tid >> 6] = ss;
    __syncthreads();
    const float total = sbuf[0] + sbuf[1] + sbuf[2] + sbuf[3];
    const float inv = 1.f / fmaxf(sqrtf(total), 1e-12f);

    float* outp = (isV ? Vout : Aout) + (size_t)r * 512;
    outp[c0] = v0 * inv;
    outp[c1] = v1 * inv;
}

// ---------- zero den/num accumulators ----------
__global__ __launch_bounds__(512) void zero_kernel(float* __restrict__ p) {
    p[threadIdx.x] = 0.f;
}

// ---------- a1.a2 and v1.v2 dots -> num += exp(dot) ----------
__global__ __launch_bounds__(256) void dots_kernel(
    const float* __restrict__ A, const float* __restrict__ V,
    float* __restrict__ num)
{
    const int b = blockIdx.x;            // 0..511
    const int i = b & 255;
    const float* X = (b < 256) ? A : V;
    const float* x = X + (size_t)i * 512;
    const float* y = X + (size_t)(i + 256) * 512;
    const int tid = threadIdx.x;
    float d = x[tid] * y[tid] + x[tid + 256] * y[tid + 256];
    #pragma unroll
    for (int off = 32; off > 0; off >>= 1) d += __shfl_down(d, off);
    __shared__ float sbuf[4];
    if ((tid & 63) == 0) sbuf[tid >> 6] = d;
    __syncthreads();
    if (tid == 0) atomicAdd(num + i, __expf(sbuf[0] + sbuf[1] + sbuf[2] + sbuf[3]));
}

// ---------- final: loss = mean(log den - log num) ----------
__global__ __launch_bounds__(256) void final_kernel(
    const float* __restrict__ den, const float* __restrict__ num,
    float* __restrict__ out)
{
    const int tid = threadIdx.x;
    float v = logf(den[tid]) - logf(num[tid]);
    #pragma unroll
    for (int off = 32; off > 0; off >>= 1) v += __shfl_down(v, off);
    __shared__ float sbuf[4];
    if ((tid & 63) == 0) sbuf[tid >> 6] = v;
    __syncthreads();
    if (tid == 0) out[0] = (sbuf[0] + sbuf[1] + sbuf[2] + sbuf[3]) * (1.f / 256.f);
}

// ---------- launch ----------
extern "C" void kernel_launch(void* const* d_in, const int* in_sizes, int n_in,
                              void* d_out, int out_size, void* d_ws, size_t ws_size,
                              hipStream_t stream)
{
    (void)in_sizes; (void)n_in; (void)out_size; (void)ws_size;
    const float* a_1 = (const float*)d_in[0];
    const float* v_1 = (const float*)d_in[1];
    const float* a_2 = (const float*)d_in[2];
    const float* v_2 = (const float*)d_in[3];
    const float* W_a = (const float*)d_in[4];
    const float* W_v = (const float*)d_in[5];
    float* out = (float*)d_out;

    float* ws      = (float*)d_ws;
    float* partV   = ws;                                     // 16 MB
    float* partA   = partV + (size_t)KSPLIT_V * 262144;      // 4 MB
    float* Anorm   = partA + (size_t)KSPLIT_A * 262144;      // 1 MB
    float* Vnorm   = Anorm + 262144;                         // 1 MB
    float* den     = Vnorm + 262144;                         // 256 f
    float* num     = den + 256;                              // 256 f

    zero_kernel<<<1, 512, 0, stream>>>(den);  // zeros den[256] + num[256]
    mm_kernel<0><<<256, 512, 0, stream>>>(v_1, v_2, W_v, partV, nullptr, nullptr);
    mm_kernel<1><<<64, 512, 0, stream>>>(a_1, a_2, W_a, partA, nullptr, nullptr);
    norm_kernel<<<1024, 256, 0, stream>>>(partA, partV, Anorm, Vnorm);
    mm_kernel<2><<<16, 512, 0, stream>>>(Anorm, Anorm + 256 * 512, Vnorm, nullptr, den, num);
    dots_kernel<<<512, 256, 0, stream>>>(Anorm, Vnorm, num);
    final_kernel<<<1, 256, 0, stream>>>(den, num, out);
}

// Round 4
// 176.018 us; speedup vs baseline: 1.5273x; 1.1311x over previous
//
#include <hip/hip_runtime.h>

typedef __attribute__((ext_vector_type(8))) short bf16x8;   // 8 bf16 (4 VGPRs)
typedef __attribute__((ext_vector_type(4))) float f32x4;    // MFMA accumulator

#define KSPLIT_V 16
#define KSPLIT_A 4

// pack two f32 -> one dword of 2 bf16 (RNE), single HW instruction
__device__ __forceinline__ unsigned int pk2(float a, float b) {
    unsigned int r;
    asm("v_cvt_pk_bf16_f32 %0, %1, %2" : "=v"(r) : "v"(a), "v"(b));
    return r;
}

// ---------------------------------------------------------------------------
// MODE 0: visual GEMM  (A = cropped visual, B = W_v k-major), partials out
// MODE 1: audio  GEMM  (A = audio,          B = W_a k-major), partials out
// MODE 2: similarity   (A = Anorm rows, B = Vnorm rows), exp/rowsum/diag out
// Tile 64x64, BK=32, 256 threads = 4 waves (2x2 of 32x32).
// Double-buffered LDS; loads for t+1 issued at top of iter t (full-iter cover).
// ---------------------------------------------------------------------------
template<int MODE>
__global__ __launch_bounds__(256, 4) void mm_kernel(
    const float* __restrict__ s1, const float* __restrict__ s2,
    const float* __restrict__ Bsrc, float* __restrict__ outp,
    float* __restrict__ den, float* __restrict__ num)
{
    __shared__ uint4 As[2][256];   // [buf][kb(4)][row(64)] 8-k bf16 units, XOR swizzle
    __shared__ uint4 Bs[2][256];   // [buf][kb(4)][col(64)]

    const int tid = threadIdx.x;
    const int blk = blockIdx.x;

    int m0, n0, k0, nsteps, z = 0;
    if (MODE == 0) {
        // XCD-chunked: xcd gets 128 consecutive lin -> 2 whole z-slices resident
        const int lin = (blk & 7) * 128 + (blk >> 3);
        z  = lin >> 6;
        m0 = ((lin >> 3) & 7) * 64;
        n0 = (lin & 7) * 64;
        k0 = z * 4320;              // 4320 = 69120/16
        nsteps = 135;
    } else if (MODE == 1) {
        z  = blk >> 6;
        m0 = ((blk >> 3) & 7) * 64;
        n0 = (blk & 7) * 64;
        k0 = z * 320;               // 1280/4
        nsteps = 10;
    } else {
        m0 = (blk >> 3) * 64;
        n0 = (blk & 7) * 64;
        k0 = 0;
        nsteps = 16;                // K = 512
    }
    if (MODE != 2) outp += (size_t)z * (512 * 512);

    const int ROWSTR = (MODE == 0) ? 138240 : (MODE == 1 ? 1280 : 512);

    // --- staging thread mapping (one 8-k bf16 unit per thread per operand)
    const int a_row = tid >> 2;        // 0..63
    const int a_kb  = tid & 3;         // 0..3
    const int b_col = tid & 63;        // 0..63
    const int b_kb  = tid >> 6;        // 0..3
    const int a_u = (a_kb * 64 + a_row) ^ (a_kb << 1);
    const int b_u = (b_kb * 64 + b_col) ^ (b_kb << 1);

    const int grow = m0 + a_row;
    const float* abase = (grow < 256) ? (s1 + (size_t)grow * ROWSTR)
                                      : (s2 + (size_t)(grow - 256) * ROWSTR);
    // crop mapping (MODE 0): within a 4608-k chunk the source is CONTIGUOUS:
    // off = c*46080 + t*9216 + 4608 + j,  j = k - (t*3+c)*4608
    int aoff, jj = 0, kglob = k0;
    if (MODE == 0) {
        const int ph = k0 / 4608;
        jj = k0 - ph * 4608;
        const int c = ph % 3, t = ph / 3;
        aoff = c * 46080 + t * 9216 + 4608 + jj + a_kb * 8;
    } else {
        aoff = k0 + a_kb * 8;
    }

    const float* bptr;
    if (MODE == 2) bptr = Bsrc + (size_t)(n0 + b_col) * 512 + b_kb * 8;
    else           bptr = Bsrc + (size_t)(k0 + b_kb * 8) * 512 + n0 + b_col;

    // --- wave tiling: 4 waves = 2x2 of 32x32
    const int lane = tid & 63;
    const int wid  = tid >> 6;
    const int wrow = (wid >> 1) * 32;
    const int wcol = (wid & 1) * 32;
    const int l15  = lane & 15;
    const int lk   = lane >> 4;

    int ra[2], rb[2];
    #pragma unroll
    for (int m = 0; m < 2; ++m) ra[m] = (lk * 64 + wrow + m * 16 + l15) ^ (lk << 1);
    #pragma unroll
    for (int n = 0; n < 2; ++n) rb[n] = (lk * 64 + wcol + n * 16 + l15) ^ (lk << 1);

    f32x4 acc[2][2];
    #pragma unroll
    for (int m = 0; m < 2; ++m)
        #pragma unroll
        for (int n = 0; n < 2; ++n) acc[m][n] = f32x4{0.f, 0.f, 0.f, 0.f};

    // --- prologue: load step 0 into regs
    float4 A0 = *(const float4*)(abase + aoff);
    float4 A1 = *(const float4*)(abase + aoff + 4);
    float4 B0, B1; float bsr[8];
    if (MODE == 2) {
        B0 = *(const float4*)bptr; B1 = *(const float4*)(bptr + 4);
    } else {
        #pragma unroll
        for (int j = 0; j < 8; ++j) bsr[j] = bptr[(size_t)j * 512];
    }

    for (int ks = 0; ks < nsteps; ++ks) {
        const int cur = ks & 1;

        // (1) issue loads for step t+1 FIRST -> in flight across pack+barrier+MFMA
        const bool more = (ks + 1 < nsteps);
        float4 A0n, A1n, B0n, B1n; float bsn[8];
        if (more) {
            kglob += 32;
            if (MODE == 0) {
                aoff += 32; jj += 32;
                if (jj == 4608) {            // rare, block-uniform
                    jj = 0;
                    const int ph = kglob / 4608;
                    const int c = ph % 3, t = ph / 3;
                    aoff = c * 46080 + t * 9216 + 4608 + a_kb * 8;
                }
            } else {
                aoff += 32;
            }
            A0n = *(const float4*)(abase + aoff);
            A1n = *(const float4*)(abase + aoff + 4);
            if (MODE == 2) {
                bptr += 32;
                B0n = *(const float4*)bptr; B1n = *(const float4*)(bptr + 4);
            } else {
                bptr += 32 * 512;
                #pragma unroll
                for (int j = 0; j < 8; ++j) bsn[j] = bptr[(size_t)j * 512];
            }
        }

        // (2) pack current regs -> LDS[cur] (counted vmcnt: only waits on step-t loads)
        uint4 pa;
        pa.x = pk2(A0.x, A0.y); pa.y = pk2(A0.z, A0.w);
        pa.z = pk2(A1.x, A1.y); pa.w = pk2(A1.z, A1.w);
        As[cur][a_u] = pa;
        uint4 pb;
        if (MODE == 2) {
            pb.x = pk2(B0.x, B0.y); pb.y = pk2(B0.z, B0.w);
            pb.z = pk2(B1.x, B1.y); pb.w = pk2(B1.z, B1.w);
        } else {
            pb.x = pk2(bsr[0], bsr[1]); pb.y = pk2(bsr[2], bsr[3]);
            pb.z = pk2(bsr[4], bsr[5]); pb.w = pk2(bsr[6], bsr[7]);
        }
        Bs[cur][b_u] = pb;
        __syncthreads();

        // (3) compute step t from LDS[cur]
        bf16x8 af[2], bfr[2];
        #pragma unroll
        for (int m = 0; m < 2; ++m) af[m] = __builtin_bit_cast(bf16x8, As[cur][ra[m]]);
        #pragma unroll
        for (int n = 0; n < 2; ++n) bfr[n] = __builtin_bit_cast(bf16x8, Bs[cur][rb[n]]);
        #pragma unroll
        for (int m = 0; m < 2; ++m)
            #pragma unroll
            for (int n = 0; n < 2; ++n)
                acc[m][n] = __builtin_amdgcn_mfma_f32_16x16x32_bf16(af[m], bfr[n], acc[m][n], 0, 0, 0);

        // (4) roll prefetch regs (no second barrier: next pack hits the other buffer)
        if (more) {
            A0 = A0n; A1 = A1n;
            if (MODE == 2) { B0 = B0n; B1 = B1n; }
            else {
                #pragma unroll
                for (int j = 0; j < 8; ++j) bsr[j] = bsn[j];
            }
        }
    }

    // --- epilogue.  C/D layout: col = lane&15, row = (lane>>4)*4 + reg
    if (MODE != 2) {
        #pragma unroll
        for (int m = 0; m < 2; ++m)
            #pragma unroll
            for (int n = 0; n < 2; ++n) {
                const int col = n0 + wcol + n * 16 + l15;
                #pragma unroll
                for (int r = 0; r < 4; ++r) {
                    const int row = m0 + wrow + m * 16 + lk * 4 + r;
                    outp[(size_t)row * 512 + col] = acc[m][n][r];
                }
            }
    } else {
        // S[row,col] = a_row . v_col ; den[row&255] += sum_col exp(S);
        // diagonal-family terms into num[row&255]
        #pragma unroll
        for (int m = 0; m < 2; ++m) {
            float rs[4] = {0.f, 0.f, 0.f, 0.f};
            #pragma unroll
            for (int n = 0; n < 2; ++n) {
                const int col = n0 + wcol + n * 16 + l15;
                #pragma unroll
                for (int r = 0; r < 4; ++r) {
                    const int row = m0 + wrow + m * 16 + lk * 4 + r;
                    const float e = __expf(acc[m][n][r]);
                    rs[r] += e;
                    if (((row - col) & 255) == 0) atomicAdd(num + (row & 255), e);
                }
            }
            #pragma unroll
            for (int r = 0; r < 4; ++r) {
                float v = rs[r];
                v += __shfl_xor(v, 1);
                v += __shfl_xor(v, 2);
                v += __shfl_xor(v, 4);
                v += __shfl_xor(v, 8);
                if (l15 == 0) {
                    const int row = m0 + wrow + m * 16 + lk * 4 + r;
                    atomicAdd(den + (row & 255), v);
                }
            }
        }
    }
}

// ---------- reduce split-K partials + row L2 normalization ----------
__global__ __launch_bounds__(256) void norm_kernel(
    const float* __restrict__ partA, const float* __restrict__ partV,
    float* __restrict__ Aout, float* __restrict__ Vout)
{
    const int row = blockIdx.x;          // 0..1023
    const int tid = threadIdx.x;
    const bool isV = row >= 512;
    const int r = isV ? (row - 512) : row;
    const int c0 = tid, c1 = tid + 256;

    float v0 = 0.f, v1 = 0.f;
    if (isV) {
        #pragma unroll
        for (int zz = 0; zz < KSPLIT_V; ++zz) {
            const float* p = partV + (size_t)zz * 262144 + (size_t)r * 512;
            v0 += p[c0]; v1 += p[c1];
        }
    } else {
        #pragma unroll
        for (int zz = 0; zz < KSPLIT_A; ++zz) {
            const float* p = partA + (size_t)zz * 262144 + (size_t)r * 512;
            v0 += p[c0]; v1 += p[c1];
        }
    }

    float ss = v0 * v0 + v1 * v1;
    #pragma unroll
    for (int off = 32; off > 0; off >>= 1) ss += __shfl_down(ss, off);
    __shared__ float sbuf[4];
    if ((tid & 63) == 0) sbuf[tid >> 6] = ss;
    __syncthreads();
    const float total = sbuf[0] + sbuf[1] + sbuf[2] + sbuf[3];
    const float inv = 1.f / fmaxf(sqrtf(total), 1e-12f);

    float* outp = (isV ? Vout : Aout) + (size_t)r * 512;
    outp[c0] = v0 * inv;
    outp[c1] = v1 * inv;
}

// ---------- zero den/num accumulators ----------
__global__ __launch_bounds__(512) void zero_kernel(float* __restrict__ p) {
    p[threadIdx.x] = 0.f;
}

// ---------- a1.a2 and v1.v2 dots -> num += exp(dot) ----------
__global__ __launch_bounds__(256) void dots_kernel(
    const float* __restrict__ A, const float* __restrict__ V,
    float* __restrict__ num)
{
    const int b = blockIdx.x;            // 0..511
    const int i = b & 255;
    const float* X = (b < 256) ? A : V;
    const float* x = X + (size_t)i * 512;
    const float* y = X + (size_t)(i + 256) * 512;
    const int tid = threadIdx.x;
    float d = x[tid] * y[tid] + x[tid + 256] * y[tid + 256];
    #pragma unroll
    for (int off = 32; off > 0; off >>= 1) d += __shfl_down(d, off);
    __shared__ float sbuf[4];
    if ((tid & 63) == 0) sbuf[tid >> 6] = d;
    __syncthreads();
    if (tid == 0) atomicAdd(num + i, __expf(sbuf[0] + sbuf[1] + sbuf[2] + sbuf[3]));
}

// ---------- final: loss = mean(log den - log num) ----------
__global__ __launch_bounds__(256) void final_kernel(
    const float* __restrict__ den, const float* __restrict__ num,
    float* __restrict__ out)
{
    const int tid = threadIdx.x;
    float v = logf(den[tid]) - logf(num[tid]);
    #pragma unroll
    for (int off = 32; off > 0; off >>= 1) v += __shfl_down(v, off);
    __shared__ float sbuf[4];
    if ((tid & 63) == 0) sbuf[tid >> 6] = v;
    __syncthreads();
    if (tid == 0) out[0] = (sbuf[0] + sbuf[1] + sbuf[2] + sbuf[3]) * (1.f / 256.f);
}

// ---------- launch ----------
extern "C" void kernel_launch(void* const* d_in, const int* in_sizes, int n_in,
                              void* d_out, int out_size, void* d_ws, size_t ws_size,
                              hipStream_t stream)
{
    (void)in_sizes; (void)n_in; (void)out_size; (void)ws_size;
    const float* a_1 = (const float*)d_in[0];
    const float* v_1 = (const float*)d_in[1];
    const float* a_2 = (const float*)d_in[2];
    const float* v_2 = (const float*)d_in[3];
    const float* W_a = (const float*)d_in[4];
    const float* W_v = (const float*)d_in[5];
    float* out = (float*)d_out;

    float* ws      = (float*)d_ws;
    float* partV   = ws;                                     // 16 MB
    float* partA   = partV + (size_t)KSPLIT_V * 262144;      // 4 MB
    float* Anorm   = partA + (size_t)KSPLIT_A * 262144;      // 1 MB
    float* Vnorm   = Anorm + 262144;                         // 1 MB
    float* den     = Vnorm + 262144;                         // 256 f
    float* num     = den + 256;                              // 256 f

    zero_kernel<<<1, 512, 0, stream>>>(den);  // zeros den[256] + num[256]
    mm_kernel<0><<<1024, 256, 0, stream>>>(v_1, v_2, W_v, partV, nullptr, nullptr);
    mm_kernel<1><<<256, 256, 0, stream>>>(a_1, a_2, W_a, partA, nullptr, nullptr);
    norm_kernel<<<1024, 256, 0, stream>>>(partA, partV, Anorm, Vnorm);
    mm_kernel<2><<<64, 256, 0, stream>>>(Anorm, Anorm + 256 * 512, Vnorm, nullptr, den, num);
    dots_kernel<<<512, 256, 0, stream>>>(Anorm, Vnorm, num);
    final_kernel<<<1, 256, 0, stream>>>(den, num, out);
}